// Round 16
// baseline (619.755 us; speedup 1.0000x reference)
//
#include <hip/hip_runtime.h>
#include <hip/hip_bf16.h>
#include <math.h>

#define NSPLIT 4096
#define NVQ    12288
#define NTOK   16384
#define CH     256
#define NH     8
#define DHD    32
#define NL     4
#define PW     256
#define HIDN   1024
#define DVQ    32
#define VQG    4
#define VQS    256

typedef __attribute__((ext_vector_type(8))) short bf16x8;
typedef __attribute__((ext_vector_type(4))) float f32x4;

typedef const __attribute__((address_space(1))) void* gas_ptr;
typedef __attribute__((address_space(3))) void* las_ptr;
#define GLD16(g, s) __builtin_amdgcn_global_load_lds((gas_ptr)(g), (las_ptr)(s), 16, 0, 0)

static __device__ __forceinline__ unsigned pack2bf(float a, float b) {
    __hip_bfloat16 ha = __float2bfloat16(a), hb = __float2bfloat16(b);
    return ((unsigned)*(unsigned short*)&hb << 16) | *(unsigned short*)&ha;
}
static __device__ __forceinline__ float bf2f(unsigned short s) {
    unsigned u = (unsigned)s << 16;
    return *(float*)&u;
}
static __device__ __forceinline__ unsigned short f2bfu(float f) {
    __hip_bfloat16 h = __float2bfloat16(f);
    return *(unsigned short*)&h;
}

// ------- all weight transposes + mask dtype detect (block 832) in one launch ----------
__global__ void k_wt_all(const float* __restrict__ qkv_w, const float* __restrict__ attn_w,
                         const float* __restrict__ fc1_w, const float* __restrict__ fc2_w,
                         const float* __restrict__ vq_w,
                         short* __restrict__ qkvT, short* __restrict__ attnT,
                         short* __restrict__ fc1T, short* __restrict__ fc2T,
                         short* __restrict__ vqT,
                         const void* __restrict__ mask_raw, int* __restrict__ mode) {
    int b = blockIdx.x;
    if (b == 832) {
        __shared__ int c_even, c_odd, c_0100;
        const unsigned short* u16 = (const unsigned short*)mask_raw;
        if (threadIdx.x == 0) { c_even = 0; c_odd = 0; c_0100 = 0; }
        __syncthreads();
        int le = 0, lo = 0, l01 = 0;
        for (int i = threadIdx.x; i < 8192; i += 256) {
            unsigned short v = u16[i];
            if (v == 0x3F80u) { if (i & 1) lo++; else le++; }
            if (v == 0x0100u) l01++;
        }
        atomicAdd(&c_even, le); atomicAdd(&c_odd, lo); atomicAdd(&c_0100, l01);
        __syncthreads();
        if (threadIdx.x == 0) {
            int m;
            if      (c_even > 500) m = 2;   // bf16
            else if (c_odd  > 500) m = 3;   // f32
            else if (c_0100 > 500) m = 1;   // u8/bool
            else                   m = 0;   // int32
            *mode = m;
        }
        return;
    }
    const float* W; short* Wt; int K, N, tn, tk;
    if (b < 192)      { int r = b;       int z = r / 48; r %= 48; K = 256;  N = 768;
                        tk = r / 12; tn = r % 12;
                        W = qkv_w + (size_t)z * K * N; Wt = qkvT + (size_t)z * K * N; }
    else if (b < 256) { int r = b - 192; int z = r / 16; r %= 16; K = 256;  N = 256;
                        tk = r / 4;  tn = r % 4;
                        W = attn_w + (size_t)z * K * N; Wt = attnT + (size_t)z * K * N; }
    else if (b < 512) { int r = b - 256; int z = r / 64; r %= 64; K = 256;  N = 1024;
                        tk = r / 16; tn = r % 16;
                        W = fc1_w + (size_t)z * K * N; Wt = fc1T + (size_t)z * K * N; }
    else if (b < 768) { int r = b - 512; int z = r / 64; r %= 64; K = 1024; N = 256;
                        tk = r / 4;  tn = r % 4;
                        W = fc2_w + (size_t)z * K * N; Wt = fc2T + (size_t)z * K * N; }
    else              { int r = b - 768; K = 256; N = 1024;
                        tk = r / 16; tn = r % 16; W = vq_w; Wt = vqT; }
    __shared__ float t[64][65];
    int bn = tn * 64, bk = tk * 64, tid = threadIdx.x;
#pragma unroll
    for (int it = 0; it < 16; ++it) {
        int idx = it * 256 + tid; int r = idx >> 6, c = idx & 63;
        t[r][c] = W[(size_t)(bk + r) * N + bn + c];
    }
    __syncthreads();
#pragma unroll
    for (int it = 0; it < 16; ++it) {
        int idx = it * 256 + tid; int r = idx >> 6, c = idx & 63;
        __hip_bfloat16 h = __float2bfloat16(t[c][r]);
        Wt[(size_t)(bn + r) * K + bk + c] = *(short*)&h;
    }
}

// ---- fused embed + mask decode + d2b gather + pos emb + LN1(layer0); bf16 outs -------
__global__ void k_embed_gather(const int* __restrict__ split, const float* __restrict__ zq,
                               const int* __restrict__ category, const int* __restrict__ batch_id,
                               const void* __restrict__ mask_raw, const int* __restrict__ mode,
                               int* __restrict__ mask_i, const int* __restrict__ d2b,
                               const float* __restrict__ split_emb, const float* __restrict__ class_emb,
                               const float* __restrict__ vq_proj_w, const float* __restrict__ vq_proj_b,
                               const float* __restrict__ ln1s, const float* __restrict__ ln1b,
                               unsigned short* __restrict__ xbv, unsigned short* __restrict__ hb) {
    int j = blockIdx.x, c = threadIdx.x;
    int i = d2b[j];
    int m = *mode, mv;
    if      (m == 0) mv = ((const int*)mask_raw)[i] != 0;
    else if (m == 1) mv = ((const unsigned char*)mask_raw)[i] != 0;
    else if (m == 2) mv = ((const unsigned short*)mask_raw)[i] != 0;
    else             mv = ((const unsigned int*)mask_raw)[i] != 0;
    if (c == 0) mask_i[i] = mv;
    float v;
    if (mv) {
        v = class_emb[category[batch_id[i]] * CH + c];
    } else if (i < NSPLIT) {
        v = split_emb[split[i] * CH + c];
    } else {
        const float* z = zq + (size_t)(i - NSPLIT) * DVQ;
        float acc = vq_proj_b[c];
#pragma unroll
        for (int k = 0; k < DVQ; k++) acc += z[k] * vq_proj_w[k * CH + c];
        v = acc;
    }
    const float kneg = -0.07195578415606394f;  // -ln(10000)/128
    float jf = (float)j, pe;
    if (c < 128) { float f = expf(c * kneg);         pe = sinf(jf * f); }
    else         { float f = expf((c - 128) * kneg); pe = cosf(jf * f); }
    v += pe;
    float s = v, sq = v * v;
#pragma unroll
    for (int o = 32; o; o >>= 1) { s += __shfl_xor(s, o); sq += __shfl_xor(sq, o); }
    __shared__ float ps[4], pq[4];
    if ((c & 63) == 0) { ps[c >> 6] = s; pq[c >> 6] = sq; }
    __syncthreads();
    float S = ps[0] + ps[1] + ps[2] + ps[3];
    float Q = pq[0] + pq[1] + pq[2] + pq[3];
    float mean = S * (1.0f / CH);
    float var  = Q * (1.0f / CH) - mean * mean;
    float rsf = rsqrtf(var + 1e-5f);
    xbv[(size_t)j * CH + c] = f2bfu(v);
    hb[(size_t)j * CH + c]  = f2bfu((v - mean) * rsf * ln1s[c] + ln1b[c]);
}

// ---------------- MFMA bf16 GEMM 128x128, BK=64, swapped-operand epilogue --------------
template <int GELU>
__global__ __launch_bounds__(256, 4) void k_mm(
    const short* __restrict__ A, const short* __restrict__ Bt,
    const float* __restrict__ bias, unsigned short* __restrict__ outB,
    int N, int K) {
    __shared__ short As[2][128 * 32];
    __shared__ short Bs[2][128 * 32];
    const int tid = threadIdx.x;
    const int w = tid >> 6, l = tid & 63;
    const int bm = blockIdx.y * 128, bn = blockIdx.x * 128;
    const int wr = w >> 1, wc = w & 1;
    const int q = l >> 4, rA = l & 15;
    const int srow = w * 16 + (l >> 2);
    const int sx = ((l & 3) ^ ((l >> 2) & 3)) * 8;
    const int fx = (q ^ (rA & 3)) * 8;

    const short* gA0 = A + (size_t)(bm + srow) * K + sx;
    const short* gA1 = A + (size_t)(bm + srow + 64) * K + sx;
    const short* gB0 = Bt + (size_t)(bn + srow) * K + sx;
    const short* gB1 = Bt + (size_t)(bn + srow + 64) * K + sx;
    short* lA0 = &As[0][w * 16 * 32];
    short* lA1 = &As[0][(64 + w * 16) * 32];
    short* lA0h = &As[1][w * 16 * 32];
    short* lA1h = &As[1][(64 + w * 16) * 32];
    short* lB0 = &Bs[0][w * 16 * 32];
    short* lB1 = &Bs[0][(64 + w * 16) * 32];
    short* lB0h = &Bs[1][w * 16 * 32];
    short* lB1h = &Bs[1][(64 + w * 16) * 32];

    f32x4 acc[4][4] = {};

    for (int k0 = 0; k0 < K; k0 += 64) {
        GLD16(gA0 + k0, lA0);       GLD16(gA1 + k0, lA1);
        GLD16(gA0 + k0 + 32, lA0h); GLD16(gA1 + k0 + 32, lA1h);
        GLD16(gB0 + k0, lB0);       GLD16(gB1 + k0, lB1);
        GLD16(gB0 + k0 + 32, lB0h); GLD16(gB1 + k0 + 32, lB1h);
        __syncthreads();
#pragma unroll
        for (int s = 0; s < 2; s++) {
            bf16x8 a[4], b[4];
#pragma unroll
            for (int m = 0; m < 4; m++)
                a[m] = *(const bf16x8*)(&As[s][(wr * 64 + m * 16 + rA) * 32 + fx]);
#pragma unroll
            for (int n = 0; n < 4; n++)
                b[n] = *(const bf16x8*)(&Bs[s][(wc * 64 + n * 16 + rA) * 32 + fx]);
#pragma unroll
            for (int m = 0; m < 4; m++)
#pragma unroll
                for (int n = 0; n < 4; n++)
                    acc[m][n] = __builtin_amdgcn_mfma_f32_16x16x32_bf16(b[n], a[m], acc[m][n], 0, 0, 0);
        }
        __syncthreads();
    }

#pragma unroll
    for (int m = 0; m < 4; m++) {
        int row = bm + wr * 64 + m * 16 + rA;
#pragma unroll
        for (int n = 0; n < 4; n++) {
            int colb = bn + wc * 64 + n * 16 + q * 4;
            float4 bv = *(const float4*)(bias + colb);
            float v0 = acc[m][n][0] + bv.x;
            float v1 = acc[m][n][1] + bv.y;
            float v2 = acc[m][n][2] + bv.z;
            float v3 = acc[m][n][3] + bv.w;
            if (GELU) {
                float t0 = tanhf(0.7978845608028654f * (v0 + 0.044715f * v0 * v0 * v0));
                float t1 = tanhf(0.7978845608028654f * (v1 + 0.044715f * v1 * v1 * v1));
                float t2 = tanhf(0.7978845608028654f * (v2 + 0.044715f * v2 * v2 * v2));
                float t3 = tanhf(0.7978845608028654f * (v3 + 0.044715f * v3 * v3 * v3));
                v0 = 0.5f * v0 * (1.0f + t0); v1 = 0.5f * v1 * (1.0f + t1);
                v2 = 0.5f * v2 * (1.0f + t2); v3 = 0.5f * v3 * (1.0f + t3);
            }
            ushort4 st = { f2bfu(v0), f2bfu(v1), f2bfu(v2), f2bfu(v3) };
            *(ushort4*)(outB + (size_t)row * N + colb) = st;
        }
    }
}

// ---- full-row GEMM, NO LDS staging: fragments direct from L2/L1; no K-loop barriers ---
// BM=32 x BN=256, 8 waves x 32-col slices. LNOUT: 1 = h_out=LN; 2 = scatter + split-CE.
template <int LNOUT>
__global__ __launch_bounds__(512, 2) void k_mm_row(
    const short* __restrict__ A, const short* __restrict__ Bt,
    const float* __restrict__ bias, unsigned short* __restrict__ xbv,
    const float* __restrict__ lns, const float* __restrict__ lnb,
    unsigned short* __restrict__ h_out, const int* __restrict__ d2b, int K,
    const int* __restrict__ split, const int* __restrict__ mask_i,
    const float* __restrict__ sw, const float* __restrict__ sb,
    float* __restrict__ sce) {
    __shared__ float part[2][8][32];
    const int tid = threadIdx.x;
    const int w = tid >> 6, l = tid & 63;
    const int bm = blockIdx.x * 32;
    const int q = l >> 4, rA = l & 15;

    // direct-global fragment pointers (natural chunk order; same per-lane on both sides)
    const short* pA0 = A + (size_t)(bm + rA) * K + q * 8;        // m=0 row
    const short* pA1 = A + (size_t)(bm + 16 + rA) * K + q * 8;   // m=1 row
    const short* pB0 = Bt + (size_t)(w * 32 + rA) * K + q * 8;       // n=0
    const short* pB1 = Bt + (size_t)(w * 32 + 16 + rA) * K + q * 8;  // n=1

    f32x4 acc[2][2] = {};

#pragma unroll 4
    for (int kk = 0; kk < K; kk += 32) {
        bf16x8 a0 = *(const bf16x8*)(pA0 + kk);
        bf16x8 a1 = *(const bf16x8*)(pA1 + kk);
        bf16x8 b0 = *(const bf16x8*)(pB0 + kk);
        bf16x8 b1 = *(const bf16x8*)(pB1 + kk);
        acc[0][0] = __builtin_amdgcn_mfma_f32_16x16x32_bf16(b0, a0, acc[0][0], 0, 0, 0);
        acc[0][1] = __builtin_amdgcn_mfma_f32_16x16x32_bf16(b1, a0, acc[0][1], 0, 0, 0);
        acc[1][0] = __builtin_amdgcn_mfma_f32_16x16x32_bf16(b0, a1, acc[1][0], 0, 0, 0);
        acc[1][1] = __builtin_amdgcn_mfma_f32_16x16x32_bf16(b1, a1, acc[1][1], 0, 0, 0);
    }

    float rsum[2] = {}, rsq[2] = {};
#pragma unroll
    for (int m = 0; m < 2; m++) {
        int row = bm + m * 16 + rA;
#pragma unroll
        for (int n = 0; n < 2; n++) {
            int colb = w * 32 + n * 16 + q * 4;
            float4 bv = *(const float4*)(bias + colb);
            size_t oi = (size_t)row * CH + colb;
            ushort4 xo = *(const ushort4*)(xbv + oi);
            float v0 = acc[m][n][0] + bv.x + bf2f(xo.x);
            float v1 = acc[m][n][1] + bv.y + bf2f(xo.y);
            float v2 = acc[m][n][2] + bv.z + bf2f(xo.z);
            float v3 = acc[m][n][3] + bv.w + bf2f(xo.w);
            acc[m][n][0] = v0; acc[m][n][1] = v1; acc[m][n][2] = v2; acc[m][n][3] = v3;
            if (LNOUT != 2) {
                ushort4 st = { f2bfu(v0), f2bfu(v1), f2bfu(v2), f2bfu(v3) };
                *(ushort4*)(xbv + oi) = st;
            }
            rsum[m] += (v0 + v1) + (v2 + v3);
            rsq[m]  += (v0 * v0 + v1 * v1) + (v2 * v2 + v3 * v3);
        }
    }
    if (LNOUT) {
#pragma unroll
        for (int m = 0; m < 2; m++) {
            rsum[m] += __shfl_xor(rsum[m], 16); rsum[m] += __shfl_xor(rsum[m], 32);
            rsq[m]  += __shfl_xor(rsq[m], 16);  rsq[m]  += __shfl_xor(rsq[m], 32);
        }
        if (q == 0) {
#pragma unroll
            for (int m = 0; m < 2; m++) {
                part[0][w][m * 16 + rA] = rsum[m];
                part[1][w][m * 16 + rA] = rsq[m];
            }
        }
        __syncthreads();
#pragma unroll
        for (int m = 0; m < 2; m++) {
            int row = m * 16 + rA;
            float S = 0.f, Q = 0.f;
#pragma unroll
            for (int ww = 0; ww < 8; ww++) { S += part[0][ww][row]; Q += part[1][ww][row]; }
            float mean = S * (1.0f / CH);
            float var  = Q * (1.0f / CH) - mean * mean;
            float rsf = rsqrtf(var + 1e-5f);
            size_t orow = (LNOUT == 2) ? (size_t)d2b[bm + row] : (size_t)(bm + row);
#pragma unroll
            for (int n = 0; n < 2; n++) {
                int colb = w * 32 + n * 16 + q * 4;
                float4 sv = *(const float4*)(lns + colb);
                float4 bb = *(const float4*)(lnb + colb);
                float h0 = (acc[m][n][0] - mean) * rsf * sv.x + bb.x;
                float h1 = (acc[m][n][1] - mean) * rsf * sv.y + bb.y;
                float h2 = (acc[m][n][2] - mean) * rsf * sv.z + bb.z;
                float h3 = (acc[m][n][3] - mean) * rsf * sv.w + bb.w;
                acc[m][n][0] = h0; acc[m][n][1] = h1; acc[m][n][2] = h2; acc[m][n][3] = h3;
                ushort4 st = { f2bfu(h0), f2bfu(h1), f2bfu(h2), f2bfu(h3) };
                *(ushort4*)(h_out + orow * CH + colb) = st;
            }
        }
    }
    if (LNOUT == 2) {
        float a0[2] = {}, a1[2] = {};
#pragma unroll
        for (int m = 0; m < 2; m++) {
#pragma unroll
            for (int n = 0; n < 2; n++) {
                int colb = w * 32 + n * 16 + q * 4;
#pragma unroll
                for (int j = 0; j < 4; j++) {
                    a0[m] += acc[m][n][j] * sw[2 * (colb + j)];
                    a1[m] += acc[m][n][j] * sw[2 * (colb + j) + 1];
                }
            }
            a0[m] += __shfl_xor(a0[m], 16); a0[m] += __shfl_xor(a0[m], 32);
            a1[m] += __shfl_xor(a1[m], 16); a1[m] += __shfl_xor(a1[m], 32);
        }
        __syncthreads();
        if (q == 0) {
#pragma unroll
            for (int m = 0; m < 2; m++) {
                part[0][w][m * 16 + rA] = a0[m];
                part[1][w][m * 16 + rA] = a1[m];
            }
        }
        __syncthreads();
        if (w == 0 && q == 0) {
#pragma unroll
            for (int m = 0; m < 2; m++) {
                int row = m * 16 + rA;
                int orow = d2b[bm + row];
                if (orow < NSPLIT) {
                    float l0 = sb[0], l1 = sb[1];
#pragma unroll
                    for (int ww = 0; ww < 8; ww++) { l0 += part[0][ww][row]; l1 += part[1][ww][row]; }
                    float mx = fmaxf(l0, l1);
                    float lse = mx + logf(__expf(l0 - mx) + __expf(l1 - mx));
                    float ce = lse - (split[orow] ? l1 : l0);
                    sce[orow] = ce * (float)mask_i[orow];
                }
            }
        }
    }
}

// ---- VQ head: GEMM (BM=32) + fused softmax-CE -----------------------------------------
__global__ __launch_bounds__(256, 4) void k_vq_head(
    const short* __restrict__ A, const short* __restrict__ vqT,
    const float* __restrict__ vq_b, const int* __restrict__ targets,
    float* __restrict__ vce4) {
    __shared__ short As[2][32 * 32];
    __shared__ short Bs[2][256 * 32];
    __shared__ float part[2][4][32];
    __shared__ float tgtv[32];
    const int tid = threadIdx.x;
    const int w = tid >> 6, l = tid & 63;
    const int bm = blockIdx.x * 32;
    const int g = blockIdx.y;
    const int q = l >> 4, rA = l & 15;
    const int sx = ((l & 3) ^ ((l >> 2) & 3)) * 8;
    const int fx = (q ^ (rA & 3)) * 8;

    const short* gA = A + (size_t)(bm + (l >> 2)) * CH + sx;
    const short* gB = vqT + (size_t)(g * VQS + w * 64 + (l >> 2)) * CH + sx;

    f32x4 acc[2][4] = {};

    for (int k0 = 0; k0 < CH; k0 += 64) {
        if (w == 0) {
#pragma unroll
            for (int rg = 0; rg < 2; rg++) {
                GLD16(gA + (size_t)(rg * 16) * CH + k0,      &As[0][(rg * 16) * 32]);
                GLD16(gA + (size_t)(rg * 16) * CH + k0 + 32, &As[1][(rg * 16) * 32]);
            }
        }
#pragma unroll
        for (int i = 0; i < 4; i++) {
            GLD16(gB + (size_t)(i * 16) * CH + k0,      &Bs[0][(w * 64 + i * 16) * 32]);
            GLD16(gB + (size_t)(i * 16) * CH + k0 + 32, &Bs[1][(w * 64 + i * 16) * 32]);
        }
        __syncthreads();
#pragma unroll
        for (int s = 0; s < 2; s++) {
            bf16x8 a[2], b[4];
#pragma unroll
            for (int m = 0; m < 2; m++)
                a[m] = *(const bf16x8*)(&As[s][(m * 16 + rA) * 32 + fx]);
#pragma unroll
            for (int n = 0; n < 4; n++)
                b[n] = *(const bf16x8*)(&Bs[s][(w * 64 + n * 16 + rA) * 32 + fx]);
#pragma unroll
            for (int m = 0; m < 2; m++)
#pragma unroll
                for (int n = 0; n < 4; n++)
                    acc[m][n] = __builtin_amdgcn_mfma_f32_16x16x32_bf16(b[n], a[m], acc[m][n], 0, 0, 0);
        }
        __syncthreads();
    }

    float pm[2];
#pragma unroll
    for (int m = 0; m < 2; m++) {
        pm[m] = -1e30f;
        int row = m * 16 + rA;
        int t = targets[(size_t)(bm + row) * VQG + g];
#pragma unroll
        for (int n = 0; n < 4; n++) {
            int colb = w * 64 + n * 16 + q * 4;
            float4 bv = *(const float4*)(vq_b + g * VQS + colb);
            float v0 = acc[m][n][0] + bv.x;
            float v1 = acc[m][n][1] + bv.y;
            float v2 = acc[m][n][2] + bv.z;
            float v3 = acc[m][n][3] + bv.w;
            acc[m][n][0] = v0; acc[m][n][1] = v1; acc[m][n][2] = v2; acc[m][n][3] = v3;
            if (colb + 0 == t) tgtv[row] = v0;
            if (colb + 1 == t) tgtv[row] = v1;
            if (colb + 2 == t) tgtv[row] = v2;
            if (colb + 3 == t) tgtv[row] = v3;
            pm[m] = fmaxf(pm[m], fmaxf(fmaxf(v0, v1), fmaxf(v2, v3)));
        }
    }
#pragma unroll
    for (int m = 0; m < 2; m++) {
        pm[m] = fmaxf(pm[m], __shfl_xor(pm[m], 16));
        pm[m] = fmaxf(pm[m], __shfl_xor(pm[m], 32));
    }
    if (q == 0) {
#pragma unroll
        for (int m = 0; m < 2; m++) part[0][w][m * 16 + rA] = pm[m];
    }
    __syncthreads();
    float pmf[2], psum[2];
#pragma unroll
    for (int m = 0; m < 2; m++) {
        int row = m * 16 + rA;
        float mx = fmaxf(fmaxf(part[0][0][row], part[0][1][row]),
                         fmaxf(part[0][2][row], part[0][3][row]));
        pmf[m] = mx;
        float s = 0.f;
#pragma unroll
        for (int n = 0; n < 4; n++)
            s += __expf(acc[m][n][0] - mx) + __expf(acc[m][n][1] - mx)
               + __expf(acc[m][n][2] - mx) + __expf(acc[m][n][3] - mx);
        psum[m] = s;
    }
#pragma unroll
    for (int m = 0; m < 2; m++) {
        psum[m] += __shfl_xor(psum[m], 16);
        psum[m] += __shfl_xor(psum[m], 32);
    }
    if (q == 0) {
#pragma unroll
        for (int m = 0; m < 2; m++) part[1][w][m * 16 + rA] = psum[m];
    }
    __syncthreads();
    if (w == 0 && q == 0) {
#pragma unroll
        for (int m = 0; m < 2; m++) {
            int row = m * 16 + rA;
            float tot = part[1][0][row] + part[1][1][row] + part[1][2][row] + part[1][3][row];
            float lse = pmf[m] + logf(tot);
            vce4[(size_t)(bm + row) * VQG + g] = lse - tgtv[row];
        }
    }
}

// ------- fused QKV-GEMM + window attention; 8 waves, block = (window, head) ------------
__global__ __launch_bounds__(512, 4) void k_attn_fused(
    const unsigned short* __restrict__ hin, const short* __restrict__ Wt,
    const float* __restrict__ bias, short* __restrict__ o, int dil) {
    __shared__ short smem[40960];          // 80 KB union
    short* Asm = smem;                     // phase A: 2 x 256x32 @ 0      (32 KB)
    short* Wsm = smem + 16384;             // phase A: 2 x 96x32  @ 32 KB  (12 KB)
    short* Ql  = smem;                     // phase B: 256x32 @ 0          (16 KB)
    short* Kl  = smem + 8192;              // phase B: 256x32 @ 16 KB
    short* Vt  = smem + 16384;             // phase B: 32x256 @ 32 KB
    short* Pl  = smem + 24576;             // phase B: 8 x 32x64 @ 48 KB   (32 KB)

    const int wid = blockIdx.x, hd = blockIdx.y;
    const int tid = threadIdx.x;
    const int w = tid >> 6, l = tid & 63;
    const int g = l >> 4, c = l & 15;
    const int tbase = (wid / dil) * (PW * dil) + (wid % dil);
    const int sx = ((l & 3) ^ ((l >> 2) & 3)) * 8;
    const int fx = (g ^ (c & 3)) * 8;

    // ---------------- phase A: QKV mini-GEMM ----------------
    f32x4 acc[2][6] = {};
    {
        const int lr = l >> 2;
        const int rw = w * 12 + lr;
        const int seg = rw >> 5, within = rw & 31;
        const short* gW = Wt + (size_t)(seg * 256 + hd * 32 + within) * CH + sx;
        for (int k0 = 0; k0 < CH; k0 += 64) {
#pragma unroll
            for (int h16 = 0; h16 < 2; h16++) {
                int row = w * 32 + h16 * 16 + lr;
                const unsigned short* src = hin + (size_t)(tbase + row * dil) * CH + k0 + sx;
                GLD16(src,      Asm + (w * 32 + h16 * 16) * 32);
                GLD16(src + 32, Asm + 8192 + (w * 32 + h16 * 16) * 32);
            }
            if (l < 48) {
                GLD16(gW + k0,      Wsm + (w * 12) * 32);
                GLD16(gW + k0 + 32, Wsm + 3072 + (w * 12) * 32);
            }
            __syncthreads();
#pragma unroll
            for (int s = 0; s < 2; s++) {
                bf16x8 a[2], b[6];
#pragma unroll
                for (int m = 0; m < 2; m++)
                    a[m] = *(const bf16x8*)(Asm + s * 8192 + (w * 32 + m * 16 + c) * 32 + fx);
#pragma unroll
                for (int n = 0; n < 6; n++)
                    b[n] = *(const bf16x8*)(Wsm + s * 3072 + (n * 16 + c) * 32 + fx);
#pragma unroll
                for (int m = 0; m < 2; m++)
#pragma unroll
                    for (int n = 0; n < 6; n++)
                        acc[m][n] = __builtin_amdgcn_mfma_f32_16x16x32_bf16(b[n], a[m], acc[m][n], 0, 0, 0);
            }
            __syncthreads();
        }
    }
    // ---- scatter Q,K (slot-XOR layout) and V (transposed layout) to LDS ----
#pragma unroll
    for (int m = 0; m < 2; m++) {
        int t = w * 32 + m * 16 + c;
#pragma unroll
        for (int n = 0; n < 6; n++) {
            int seg = n >> 1, n1 = n & 1;
            int colb = n1 * 16 + g * 4;
            float4 bv = *(const float4*)(bias + seg * 256 + hd * 32 + colb);
            float v0 = acc[m][n][0] + bv.x;
            float v1 = acc[m][n][1] + bv.y;
            float v2 = acc[m][n][2] + bv.z;
            float v3 = acc[m][n][3] + bv.w;
            if (seg < 2) {
                short* dst = (seg == 0) ? Ql : Kl;
                int slot = (n1 * 2 + (g >> 1)) ^ (t & 3);
                uint2 pk; pk.x = pack2bf(v0, v1); pk.y = pack2bf(v2, v3);
                *(uint2*)(dst + t * 32 + slot * 8 + (g & 1) * 4) = pk;
            } else {
                int d0 = colb;
                Vt[(d0 + 0) * PW + ((((t >> 3) ^ ((d0 + 0) & 7))) << 3) + (t & 7)] = (short)f2bfu(v0);
                Vt[(d0 + 1) * PW + ((((t >> 3) ^ ((d0 + 1) & 7))) << 3) + (t & 7)] = (short)f2bfu(v1);
                Vt[(d0 + 2) * PW + ((((t >> 3) ^ ((d0 + 2) & 7))) << 3) + (t & 7)] = (short)f2bfu(v2);
                Vt[(d0 + 3) * PW + ((((t >> 3) ^ ((d0 + 3) & 7))) << 3) + (t & 7)] = (short)f2bfu(v3);
            }
        }
    }
    __syncthreads();

    // ---------------- phase B: flash attention ----------------
    bf16x8 qf[2];
#pragma unroll
    for (int qt = 0; qt < 2; qt++) {
        int qrow = w * 32 + qt * 16 + c;
        qf[qt] = *(const bf16x8*)(Ql + qrow * 32 + ((g ^ (qrow & 3)) * 8));
    }

    f32x4 acco[2][2] = {};
    float m_s[2] = {-1e30f, -1e30f};
    float l_s[2] = {0.f, 0.f};
    const float scale = 0.17677669529663687f;

#pragma unroll
    for (int ch = 0; ch < 4; ch++) {
        bf16x8 kf[4];
#pragma unroll
        for (int kvt = 0; kvt < 4; kvt++) {
            int kv = ch * 64 + kvt * 16 + c;
            kf[kvt] = *(const bf16x8*)(Kl + kv * 32 + ((g ^ (kv & 3)) * 8));
        }
        f32x4 accs[4][2] = {};
#pragma unroll
        for (int kvt = 0; kvt < 4; kvt++)
#pragma unroll
            for (int qt = 0; qt < 2; qt++)
                accs[kvt][qt] = __builtin_amdgcn_mfma_f32_16x16x32_bf16(kf[kvt], qf[qt], accs[kvt][qt], 0, 0, 0);

        float fb[2];
#pragma unroll
        for (int qt = 0; qt < 2; qt++) {
            float mx = -1e30f;
#pragma unroll
            for (int kvt = 0; kvt < 4; kvt++) {
                mx = fmaxf(mx, fmaxf(fmaxf(accs[kvt][qt][0], accs[kvt][qt][1]),
                                     fmaxf(accs[kvt][qt][2], accs[kvt][qt][3])));
            }
            mx = fmaxf(mx, __shfl_xor(mx, 16));
            mx = fmaxf(mx, __shfl_xor(mx, 32));
            float mnew = fmaxf(m_s[qt], mx * scale);
            fb[qt] = __expf(m_s[qt] - mnew);
            m_s[qt] = mnew;
        }
#pragma unroll
        for (int mt = 0; mt < 2; mt++) {
            float fo = fb[mt];
#pragma unroll
            for (int r = 0; r < 4; r++) {
                acco[mt][0][r] *= fo;
                acco[mt][1][r] *= fo;
            }
        }
        float rsum[2] = {0.f, 0.f};
#pragma unroll
        for (int kvt = 0; kvt < 4; kvt++) {
            const int cchunk = kvt * 2 + (g >> 1);
            const int koff = (g & 1) << 2;
#pragma unroll
            for (int qt = 0; qt < 2; qt++) {
                float p0 = __expf(accs[kvt][qt][0] * scale - m_s[qt]);
                float p1 = __expf(accs[kvt][qt][1] * scale - m_s[qt]);
                float p2 = __expf(accs[kvt][qt][2] * scale - m_s[qt]);
                float p3 = __expf(accs[kvt][qt][3] * scale - m_s[qt]);
                rsum[qt] += (p0 + p1) + (p2 + p3);
                int qq = qt * 16 + c;
                int phys = cchunk ^ (qq & 7);
                uint2 pk; pk.x = pack2bf(p0, p1); pk.y = pack2bf(p2, p3);
                *(uint2*)(Pl + w * 2048 + qq * 64 + phys * 8 + koff) = pk;
            }
        }
#pragma unroll
        for (int qt = 0; qt < 2; qt++) {
            float s = rsum[qt];
            s += __shfl_xor(s, 16);
            s += __shfl_xor(s, 32);
            l_s[qt] = l_s[qt] * fb[qt] + s;
        }
#pragma unroll
        for (int ks = 0; ks < 2; ks++) {
            bf16x8 pa[2];
#pragma unroll
            for (int mt = 0; mt < 2; mt++) {
                int qq = mt * 16 + c;
                int phys = (ks * 4 + g) ^ (qq & 7);
                pa[mt] = *(const bf16x8*)(Pl + w * 2048 + qq * 64 + phys * 8);
            }
#pragma unroll
            for (int nt = 0; nt < 2; nt++) {
                int d = nt * 16 + c;
                int kvabs = ch * 64 + ks * 32 + g * 8;
                int phys = (kvabs >> 3) ^ (d & 7);
                bf16x8 vb = *(const bf16x8*)(Vt + d * PW + phys * 8);
#pragma unroll
                for (int mt = 0; mt < 2; mt++)
                    acco[mt][nt] = __builtin_amdgcn_mfma_f32_16x16x32_bf16(vb, pa[mt], acco[mt][nt], 0, 0, 0);
            }
        }
    }

#pragma unroll
    for (int mt = 0; mt < 2; mt++) {
        float linv = 1.0f / l_s[mt];
        int qrow = w * 32 + mt * 16 + c;
        size_t trow = (size_t)(tbase + qrow * dil) * CH + hd * DHD;
#pragma unroll
        for (int nt = 0; nt < 2; nt++) {
            ushort4 st = { f2bfu(acco[mt][nt][0] * linv), f2bfu(acco[mt][nt][1] * linv),
                           f2bfu(acco[mt][nt][2] * linv), f2bfu(acco[mt][nt][3] * linv) };
            *(ushort4*)((unsigned short*)o + trow + nt * 16 + g * 4) = st;
        }
    }
}

// ---------------- final reduction ------------------------------------------------------
__global__ void k_reduce(const float* __restrict__ sce, const float* __restrict__ vce4,
                         const int* __restrict__ mask_i, float* __restrict__ out) {
    int tid = threadIdx.x;
    float s1 = 0, s2 = 0, s3 = 0, s4 = 0;
    for (int i = tid; i < NSPLIT; i += 256) { s1 += sce[i]; s2 += (float)mask_i[i]; }
    for (int i = tid; i < NVQ; i += 256) {
        float mv = (float)mask_i[NSPLIT + i];
        float cs = vce4[i * 4 + 0] + vce4[i * 4 + 1] + vce4[i * 4 + 2] + vce4[i * 4 + 3];
        s3 += cs * 0.25f * mv;
        s4 += mv;
    }
    __shared__ float r1[256], r2[256], r3[256], r4[256];
    r1[tid] = s1; r2[tid] = s2; r3[tid] = s3; r4[tid] = s4;
    __syncthreads();
    for (int o = 128; o; o >>= 1) {
        if (tid < o) { r1[tid] += r1[tid + o]; r2[tid] += r2[tid + o];
                       r3[tid] += r3[tid + o]; r4[tid] += r4[tid + o]; }
        __syncthreads();
    }
    if (tid == 0) {
        out[0] = r1[0] / fmaxf(r2[0], 1.0f);
        out[1] = r3[0] / fmaxf(r4[0], 1.0f);
    }
}

// ======================================================================================
extern "C" void kernel_launch(void* const* d_in, const int* in_sizes, int n_in,
                              void* d_out, int out_size, void* d_ws, size_t ws_size,
                              hipStream_t stream) {
    const int*   split      = (const int*)d_in[0];
    const float* zq         = (const float*)d_in[1];
    const int*   targets_vq = (const int*)d_in[2];
    const int*   category   = (const int*)d_in[3];
    const int*   batch_id   = (const int*)d_in[4];
    const void*  mask_raw   = d_in[5];
    const int*   d2b        = (const int*)d_in[6];
    const float* split_emb  = (const float*)d_in[7];
    const float* class_emb  = (const float*)d_in[8];
    const float* vq_proj_w  = (const float*)d_in[9];
    const float* vq_proj_b  = (const float*)d_in[10];
    const float* ln1_s      = (const float*)d_in[11];
    const float* ln1_b      = (const float*)d_in[12];
    const float* qkv_w      = (const float*)d_in[13];
    const float* qkv_b      = (const float*)d_in[14];
    const float* attn_w     = (const float*)d_in[15];
    const float* attn_b     = (const float*)d_in[16];
    const float* ln2_s      = (const float*)d_in[17];
    const float* ln2_b      = (const float*)d_in[18];
    const float* fc1_w      = (const float*)d_in[19];
    const float* fc1_b      = (const float*)d_in[20];
    const float* fc2_w      = (const float*)d_in[21];
    const float* fc2_b      = (const float*)d_in[22];
    const float* lnx_s      = (const float*)d_in[23];
    const float* lnx_b      = (const float*)d_in[24];
    const float* sw         = (const float*)d_in[25];
    const float* sb         = (const float*)d_in[26];
    const float* vq_w       = (const float*)d_in[27];
    const float* vq_b       = (const float*)d_in[28];

    char* ws = (char*)d_ws;
    int* mode   = (int*)ws;
    int* mask_i = (int*)(ws + 256);
    float* sce  = (float*)(ws + 256 + 4 * NTOK);
    float* vce4 = sce + NSPLIT;
    char* p = ws + (1 << 20);
    short* qkvT = (short*)p;  p += (size_t)NL * 768 * CH * 2;
    short* attnT = (short*)p; p += (size_t)NL * CH * CH * 2;
    short* fc1T = (short*)p;  p += (size_t)NL * HIDN * CH * 2;
    short* fc2T = (short*)p;  p += (size_t)NL * CH * HIDN * 2;
    short* vqT = (short*)p;   p += (size_t)HIDN * CH * 2;
    unsigned short* xbv = (unsigned short*)p; p += (size_t)NTOK * CH * 2;
    unsigned short* h_bf = (unsigned short*)p; p += (size_t)NTOK * CH * 2;
    unsigned short* o_bf = (unsigned short*)p; p += (size_t)NTOK * CH * 2;
    short* big = (short*)p;   // fc1-out (bf16)

    k_wt_all<<<833, 256, 0, stream>>>(qkv_w, attn_w, fc1_w, fc2_w, vq_w,
                                      qkvT, attnT, fc1T, fc2T, vqT, mask_raw, mode);
    k_embed_gather<<<NTOK, 256, 0, stream>>>(split, zq, category, batch_id, mask_raw, mode,
                                             mask_i, d2b, split_emb, class_emb,
                                             vq_proj_w, vq_proj_b, ln1_s, ln1_b, xbv, h_bf);

    for (int l = 0; l < NL; l++) {
        int d = (l & 1) ? 2 : 1;
        k_attn_fused<<<dim3(NTOK / PW, NH), 512, 0, stream>>>(
            h_bf, qkvT + (size_t)l * 768 * CH, qkv_b + l * 768, (short*)o_bf, d);
        k_mm_row<1><<<NTOK / 32, 512, 0, stream>>>(
            (const short*)o_bf, attnT + (size_t)l * CH * CH, attn_b + l * CH,
            xbv, ln2_s + l * CH, ln2_b + l * CH, h_bf, nullptr, CH,
            nullptr, nullptr, nullptr, nullptr, nullptr);
        k_mm<1><<<dim3(HIDN / 128, NTOK / 128), 256, 0, stream>>>(
            (const short*)h_bf, fc1T + (size_t)l * HIDN * CH, fc1_b + l * HIDN,
            (unsigned short*)big, HIDN, CH);
        if (l < NL - 1) {
            k_mm_row<1><<<NTOK / 32, 512, 0, stream>>>(
                big, fc2T + (size_t)l * CH * HIDN, fc2_b + l * CH,
                xbv, ln1_s + (l + 1) * CH, ln1_b + (l + 1) * CH, h_bf, nullptr, HIDN,
                nullptr, nullptr, nullptr, nullptr, nullptr);
        } else {
            k_mm_row<2><<<NTOK / 32, 512, 0, stream>>>(
                big, fc2T + (size_t)l * CH * HIDN, fc2_b + l * CH,
                xbv, lnx_s, lnx_b, h_bf, d2b, HIDN,
                split, mask_i, sw, sb, sce);
        }
    }

    k_vq_head<<<dim3(NVQ / 32, VQG), 256, 0, stream>>>(
        (const short*)(h_bf + (size_t)NSPLIT * CH), vqT, vq_b, targets_vq, vce4);
    k_reduce<<<1, 256, 0, stream>>>(sce, vce4, mask_i, (float*)d_out);
}

// Round 17
// 424.462 us; speedup vs baseline: 1.4601x; 1.4601x over previous
//
#include <hip/hip_runtime.h>
#include <hip/hip_bf16.h>
#include <math.h>

#define NSPLIT 4096
#define NVQ    12288
#define NTOK   16384
#define CH     256
#define NH     8
#define DHD    32
#define NL     4
#define PW     256
#define HIDN   1024
#define DVQ    32
#define VQG    4
#define VQS    256

typedef __attribute__((ext_vector_type(8))) short bf16x8;
typedef __attribute__((ext_vector_type(4))) float f32x4;

typedef const __attribute__((address_space(1))) void* gas_ptr;
typedef __attribute__((address_space(3))) void* las_ptr;
#define GLD16(g, s) __builtin_amdgcn_global_load_lds((gas_ptr)(g), (las_ptr)(s), 16, 0, 0)

static __device__ __forceinline__ unsigned pack2bf(float a, float b) {
    __hip_bfloat16 ha = __float2bfloat16(a), hb = __float2bfloat16(b);
    return ((unsigned)*(unsigned short*)&hb << 16) | *(unsigned short*)&ha;
}
static __device__ __forceinline__ float bf2f(unsigned short s) {
    unsigned u = (unsigned)s << 16;
    return *(float*)&u;
}
static __device__ __forceinline__ unsigned short f2bfu(float f) {
    __hip_bfloat16 h = __float2bfloat16(f);
    return *(unsigned short*)&h;
}

// ------- all weight transposes + mask dtype detect (block 832) in one launch ----------
__global__ void k_wt_all(const float* __restrict__ qkv_w, const float* __restrict__ attn_w,
                         const float* __restrict__ fc1_w, const float* __restrict__ fc2_w,
                         const float* __restrict__ vq_w,
                         short* __restrict__ qkvT, short* __restrict__ attnT,
                         short* __restrict__ fc1T, short* __restrict__ fc2T,
                         short* __restrict__ vqT,
                         const void* __restrict__ mask_raw, int* __restrict__ mode) {
    int b = blockIdx.x;
    if (b == 832) {
        __shared__ int c_even, c_odd, c_0100;
        const unsigned short* u16 = (const unsigned short*)mask_raw;
        if (threadIdx.x == 0) { c_even = 0; c_odd = 0; c_0100 = 0; }
        __syncthreads();
        int le = 0, lo = 0, l01 = 0;
        for (int i = threadIdx.x; i < 8192; i += 256) {
            unsigned short v = u16[i];
            if (v == 0x3F80u) { if (i & 1) lo++; else le++; }
            if (v == 0x0100u) l01++;
        }
        atomicAdd(&c_even, le); atomicAdd(&c_odd, lo); atomicAdd(&c_0100, l01);
        __syncthreads();
        if (threadIdx.x == 0) {
            int m;
            if      (c_even > 500) m = 2;   // bf16
            else if (c_odd  > 500) m = 3;   // f32
            else if (c_0100 > 500) m = 1;   // u8/bool
            else                   m = 0;   // int32
            *mode = m;
        }
        return;
    }
    const float* W; short* Wt; int K, N, tn, tk;
    if (b < 192)      { int r = b;       int z = r / 48; r %= 48; K = 256;  N = 768;
                        tk = r / 12; tn = r % 12;
                        W = qkv_w + (size_t)z * K * N; Wt = qkvT + (size_t)z * K * N; }
    else if (b < 256) { int r = b - 192; int z = r / 16; r %= 16; K = 256;  N = 256;
                        tk = r / 4;  tn = r % 4;
                        W = attn_w + (size_t)z * K * N; Wt = attnT + (size_t)z * K * N; }
    else if (b < 512) { int r = b - 256; int z = r / 64; r %= 64; K = 256;  N = 1024;
                        tk = r / 16; tn = r % 16;
                        W = fc1_w + (size_t)z * K * N; Wt = fc1T + (size_t)z * K * N; }
    else if (b < 768) { int r = b - 512; int z = r / 64; r %= 64; K = 1024; N = 256;
                        tk = r / 4;  tn = r % 4;
                        W = fc2_w + (size_t)z * K * N; Wt = fc2T + (size_t)z * K * N; }
    else              { int r = b - 768; K = 256; N = 1024;
                        tk = r / 16; tn = r % 16; W = vq_w; Wt = vqT; }
    __shared__ float t[64][65];
    int bn = tn * 64, bk = tk * 64, tid = threadIdx.x;
#pragma unroll
    for (int it = 0; it < 16; ++it) {
        int idx = it * 256 + tid; int r = idx >> 6, c = idx & 63;
        t[r][c] = W[(size_t)(bk + r) * N + bn + c];
    }
    __syncthreads();
#pragma unroll
    for (int it = 0; it < 16; ++it) {
        int idx = it * 256 + tid; int r = idx >> 6, c = idx & 63;
        __hip_bfloat16 h = __float2bfloat16(t[c][r]);
        Wt[(size_t)(bn + r) * K + bk + c] = *(short*)&h;
    }
}

// ---- fused embed + mask decode + d2b gather + pos emb + LN1(layer0); bf16 outs -------
__global__ void k_embed_gather(const int* __restrict__ split, const float* __restrict__ zq,
                               const int* __restrict__ category, const int* __restrict__ batch_id,
                               const void* __restrict__ mask_raw, const int* __restrict__ mode,
                               int* __restrict__ mask_i, const int* __restrict__ d2b,
                               const float* __restrict__ split_emb, const float* __restrict__ class_emb,
                               const float* __restrict__ vq_proj_w, const float* __restrict__ vq_proj_b,
                               const float* __restrict__ ln1s, const float* __restrict__ ln1b,
                               unsigned short* __restrict__ xbv, unsigned short* __restrict__ hb) {
    int j = blockIdx.x, c = threadIdx.x;
    int i = d2b[j];
    int m = *mode, mv;
    if      (m == 0) mv = ((const int*)mask_raw)[i] != 0;
    else if (m == 1) mv = ((const unsigned char*)mask_raw)[i] != 0;
    else if (m == 2) mv = ((const unsigned short*)mask_raw)[i] != 0;
    else             mv = ((const unsigned int*)mask_raw)[i] != 0;
    if (c == 0) mask_i[i] = mv;
    float v;
    if (mv) {
        v = class_emb[category[batch_id[i]] * CH + c];
    } else if (i < NSPLIT) {
        v = split_emb[split[i] * CH + c];
    } else {
        const float* z = zq + (size_t)(i - NSPLIT) * DVQ;
        float acc = vq_proj_b[c];
#pragma unroll
        for (int k = 0; k < DVQ; k++) acc += z[k] * vq_proj_w[k * CH + c];
        v = acc;
    }
    const float kneg = -0.07195578415606394f;  // -ln(10000)/128
    float jf = (float)j, pe;
    if (c < 128) { float f = expf(c * kneg);         pe = sinf(jf * f); }
    else         { float f = expf((c - 128) * kneg); pe = cosf(jf * f); }
    v += pe;
    float s = v, sq = v * v;
#pragma unroll
    for (int o = 32; o; o >>= 1) { s += __shfl_xor(s, o); sq += __shfl_xor(sq, o); }
    __shared__ float ps[4], pq[4];
    if ((c & 63) == 0) { ps[c >> 6] = s; pq[c >> 6] = sq; }
    __syncthreads();
    float S = ps[0] + ps[1] + ps[2] + ps[3];
    float Q = pq[0] + pq[1] + pq[2] + pq[3];
    float mean = S * (1.0f / CH);
    float var  = Q * (1.0f / CH) - mean * mean;
    float rsf = rsqrtf(var + 1e-5f);
    xbv[(size_t)j * CH + c] = f2bfu(v);
    hb[(size_t)j * CH + c]  = f2bfu((v - mean) * rsf * ln1s[c] + ln1b[c]);
}

// ---------------- MFMA bf16 GEMM 128x128, BK=64, swapped-operand epilogue --------------
template <int GELU>
__global__ __launch_bounds__(256, 4) void k_mm(
    const short* __restrict__ A, const short* __restrict__ Bt,
    const float* __restrict__ bias, unsigned short* __restrict__ outB,
    int N, int K) {
    __shared__ short As[2][128 * 32];
    __shared__ short Bs[2][128 * 32];
    const int tid = threadIdx.x;
    const int w = tid >> 6, l = tid & 63;
    const int bm = blockIdx.y * 128, bn = blockIdx.x * 128;
    const int wr = w >> 1, wc = w & 1;
    const int q = l >> 4, rA = l & 15;
    const int srow = w * 16 + (l >> 2);
    const int sx = ((l & 3) ^ ((l >> 2) & 3)) * 8;
    const int fx = (q ^ (rA & 3)) * 8;

    const short* gA0 = A + (size_t)(bm + srow) * K + sx;
    const short* gA1 = A + (size_t)(bm + srow + 64) * K + sx;
    const short* gB0 = Bt + (size_t)(bn + srow) * K + sx;
    const short* gB1 = Bt + (size_t)(bn + srow + 64) * K + sx;
    short* lA0 = &As[0][w * 16 * 32];
    short* lA1 = &As[0][(64 + w * 16) * 32];
    short* lA0h = &As[1][w * 16 * 32];
    short* lA1h = &As[1][(64 + w * 16) * 32];
    short* lB0 = &Bs[0][w * 16 * 32];
    short* lB1 = &Bs[0][(64 + w * 16) * 32];
    short* lB0h = &Bs[1][w * 16 * 32];
    short* lB1h = &Bs[1][(64 + w * 16) * 32];

    f32x4 acc[4][4] = {};

    for (int k0 = 0; k0 < K; k0 += 64) {
        GLD16(gA0 + k0, lA0);       GLD16(gA1 + k0, lA1);
        GLD16(gA0 + k0 + 32, lA0h); GLD16(gA1 + k0 + 32, lA1h);
        GLD16(gB0 + k0, lB0);       GLD16(gB1 + k0, lB1);
        GLD16(gB0 + k0 + 32, lB0h); GLD16(gB1 + k0 + 32, lB1h);
        __syncthreads();
#pragma unroll
        for (int s = 0; s < 2; s++) {
            bf16x8 a[4], b[4];
#pragma unroll
            for (int m = 0; m < 4; m++)
                a[m] = *(const bf16x8*)(&As[s][(wr * 64 + m * 16 + rA) * 32 + fx]);
#pragma unroll
            for (int n = 0; n < 4; n++)
                b[n] = *(const bf16x8*)(&Bs[s][(wc * 64 + n * 16 + rA) * 32 + fx]);
#pragma unroll
            for (int m = 0; m < 4; m++)
#pragma unroll
                for (int n = 0; n < 4; n++)
                    acc[m][n] = __builtin_amdgcn_mfma_f32_16x16x32_bf16(b[n], a[m], acc[m][n], 0, 0, 0);
        }
        __syncthreads();
    }

#pragma unroll
    for (int m = 0; m < 4; m++) {
        int row = bm + wr * 64 + m * 16 + rA;
#pragma unroll
        for (int n = 0; n < 4; n++) {
            int colb = bn + wc * 64 + n * 16 + q * 4;
            float4 bv = *(const float4*)(bias + colb);
            float v0 = acc[m][n][0] + bv.x;
            float v1 = acc[m][n][1] + bv.y;
            float v2 = acc[m][n][2] + bv.z;
            float v3 = acc[m][n][3] + bv.w;
            if (GELU) {
                float t0 = tanhf(0.7978845608028654f * (v0 + 0.044715f * v0 * v0 * v0));
                float t1 = tanhf(0.7978845608028654f * (v1 + 0.044715f * v1 * v1 * v1));
                float t2 = tanhf(0.7978845608028654f * (v2 + 0.044715f * v2 * v2 * v2));
                float t3 = tanhf(0.7978845608028654f * (v3 + 0.044715f * v3 * v3 * v3));
                v0 = 0.5f * v0 * (1.0f + t0); v1 = 0.5f * v1 * (1.0f + t1);
                v2 = 0.5f * v2 * (1.0f + t2); v3 = 0.5f * v3 * (1.0f + t3);
            }
            ushort4 st = { f2bfu(v0), f2bfu(v1), f2bfu(v2), f2bfu(v3) };
            *(ushort4*)(outB + (size_t)row * N + colb) = st;
        }
    }
}

// ---- full-row GEMM (BM=32 x BN=256, 8 waves x 32-col slices) + residual + row-LN ------
// LNOUT: 1 = h_out = LN(xb_new); 2 = h_out scattered via d2b + split-CE, xb store skipped.
template <int LNOUT>
__global__ __launch_bounds__(512, 4) void k_mm_row(
    const short* __restrict__ A, const short* __restrict__ Bt,
    const float* __restrict__ bias, unsigned short* __restrict__ xbv,
    const float* __restrict__ lns, const float* __restrict__ lnb,
    unsigned short* __restrict__ h_out, const int* __restrict__ d2b, int K,
    const int* __restrict__ split, const int* __restrict__ mask_i,
    const float* __restrict__ sw, const float* __restrict__ sb,
    float* __restrict__ sce) {
    __shared__ short As[2][32 * 32];
    __shared__ short Bs[2][256 * 32];
    __shared__ float part[2][8][32];
    const int tid = threadIdx.x;
    const int w = tid >> 6, l = tid & 63;
    const int bm = blockIdx.x * 32;
    const int q = l >> 4, rA = l & 15;
    const int sx = ((l & 3) ^ ((l >> 2) & 3)) * 8;
    const int fx = (q ^ (rA & 3)) * 8;

    const short* gA = A + (size_t)(bm + (l >> 2)) * K + sx;
    const short* gB = Bt + (size_t)(w * 32 + (l >> 2)) * K + sx;

    f32x4 acc[2][2] = {};

    for (int k0 = 0; k0 < K; k0 += 64) {
        if (w == 0) {
#pragma unroll
            for (int rg = 0; rg < 2; rg++) {
                GLD16(gA + (size_t)(rg * 16) * K + k0,      &As[0][(rg * 16) * 32]);
                GLD16(gA + (size_t)(rg * 16) * K + k0 + 32, &As[1][(rg * 16) * 32]);
            }
        }
#pragma unroll
        for (int i = 0; i < 2; i++) {
            GLD16(gB + (size_t)(i * 16) * K + k0,      &Bs[0][(w * 32 + i * 16) * 32]);
            GLD16(gB + (size_t)(i * 16) * K + k0 + 32, &Bs[1][(w * 32 + i * 16) * 32]);
        }
        __syncthreads();
#pragma unroll
        for (int s = 0; s < 2; s++) {
            bf16x8 a[2], b[2];
#pragma unroll
            for (int m = 0; m < 2; m++)
                a[m] = *(const bf16x8*)(&As[s][(m * 16 + rA) * 32 + fx]);
#pragma unroll
            for (int n = 0; n < 2; n++)
                b[n] = *(const bf16x8*)(&Bs[s][(w * 32 + n * 16 + rA) * 32 + fx]);
#pragma unroll
            for (int m = 0; m < 2; m++)
#pragma unroll
                for (int n = 0; n < 2; n++)
                    acc[m][n] = __builtin_amdgcn_mfma_f32_16x16x32_bf16(b[n], a[m], acc[m][n], 0, 0, 0);
        }
        __syncthreads();
    }

    float rsum[2] = {}, rsq[2] = {};
#pragma unroll
    for (int m = 0; m < 2; m++) {
        int row = bm + m * 16 + rA;
#pragma unroll
        for (int n = 0; n < 2; n++) {
            int colb = w * 32 + n * 16 + q * 4;
            float4 bv = *(const float4*)(bias + colb);
            size_t oi = (size_t)row * CH + colb;
            ushort4 xo = *(const ushort4*)(xbv + oi);
            float v0 = acc[m][n][0] + bv.x + bf2f(xo.x);
            float v1 = acc[m][n][1] + bv.y + bf2f(xo.y);
            float v2 = acc[m][n][2] + bv.z + bf2f(xo.z);
            float v3 = acc[m][n][3] + bv.w + bf2f(xo.w);
            acc[m][n][0] = v0; acc[m][n][1] = v1; acc[m][n][2] = v2; acc[m][n][3] = v3;
            if (LNOUT != 2) {
                ushort4 st = { f2bfu(v0), f2bfu(v1), f2bfu(v2), f2bfu(v3) };
                *(ushort4*)(xbv + oi) = st;
            }
            rsum[m] += (v0 + v1) + (v2 + v3);
            rsq[m]  += (v0 * v0 + v1 * v1) + (v2 * v2 + v3 * v3);
        }
    }
    if (LNOUT) {
#pragma unroll
        for (int m = 0; m < 2; m++) {
            rsum[m] += __shfl_xor(rsum[m], 16); rsum[m] += __shfl_xor(rsum[m], 32);
            rsq[m]  += __shfl_xor(rsq[m], 16);  rsq[m]  += __shfl_xor(rsq[m], 32);
        }
        if (q == 0) {
#pragma unroll
            for (int m = 0; m < 2; m++) {
                part[0][w][m * 16 + rA] = rsum[m];
                part[1][w][m * 16 + rA] = rsq[m];
            }
        }
        __syncthreads();
#pragma unroll
        for (int m = 0; m < 2; m++) {
            int row = m * 16 + rA;
            float S = 0.f, Q = 0.f;
#pragma unroll
            for (int ww = 0; ww < 8; ww++) { S += part[0][ww][row]; Q += part[1][ww][row]; }
            float mean = S * (1.0f / CH);
            float var  = Q * (1.0f / CH) - mean * mean;
            float rsf = rsqrtf(var + 1e-5f);
            size_t orow = (LNOUT == 2) ? (size_t)d2b[bm + row] : (size_t)(bm + row);
#pragma unroll
            for (int n = 0; n < 2; n++) {
                int colb = w * 32 + n * 16 + q * 4;
                float4 sv = *(const float4*)(lns + colb);
                float4 bb = *(const float4*)(lnb + colb);
                float h0 = (acc[m][n][0] - mean) * rsf * sv.x + bb.x;
                float h1 = (acc[m][n][1] - mean) * rsf * sv.y + bb.y;
                float h2 = (acc[m][n][2] - mean) * rsf * sv.z + bb.z;
                float h3 = (acc[m][n][3] - mean) * rsf * sv.w + bb.w;
                acc[m][n][0] = h0; acc[m][n][1] = h1; acc[m][n][2] = h2; acc[m][n][3] = h3;
                ushort4 st = { f2bfu(h0), f2bfu(h1), f2bfu(h2), f2bfu(h3) };
                *(ushort4*)(h_out + orow * CH + colb) = st;
            }
        }
    }
    if (LNOUT == 2) {
        float a0[2] = {}, a1[2] = {};
#pragma unroll
        for (int m = 0; m < 2; m++) {
#pragma unroll
            for (int n = 0; n < 2; n++) {
                int colb = w * 32 + n * 16 + q * 4;
#pragma unroll
                for (int j = 0; j < 4; j++) {
                    a0[m] += acc[m][n][j] * sw[2 * (colb + j)];
                    a1[m] += acc[m][n][j] * sw[2 * (colb + j) + 1];
                }
            }
            a0[m] += __shfl_xor(a0[m], 16); a0[m] += __shfl_xor(a0[m], 32);
            a1[m] += __shfl_xor(a1[m], 16); a1[m] += __shfl_xor(a1[m], 32);
        }
        __syncthreads();
        if (q == 0) {
#pragma unroll
            for (int m = 0; m < 2; m++) {
                part[0][w][m * 16 + rA] = a0[m];
                part[1][w][m * 16 + rA] = a1[m];
            }
        }
        __syncthreads();
        if (w == 0 && q == 0) {
#pragma unroll
            for (int m = 0; m < 2; m++) {
                int row = m * 16 + rA;
                int orow = d2b[bm + row];
                if (orow < NSPLIT) {
                    float l0 = sb[0], l1 = sb[1];
#pragma unroll
                    for (int ww = 0; ww < 8; ww++) { l0 += part[0][ww][row]; l1 += part[1][ww][row]; }
                    float mx = fmaxf(l0, l1);
                    float lse = mx + logf(__expf(l0 - mx) + __expf(l1 - mx));
                    float ce = lse - (split[orow] ? l1 : l0);
                    sce[orow] = ce * (float)mask_i[orow];
                }
            }
        }
    }
}

// ---- VQ head: GEMM (BM=32) + fused softmax-CE -----------------------------------------
__global__ __launch_bounds__(256, 4) void k_vq_head(
    const short* __restrict__ A, const short* __restrict__ vqT,
    const float* __restrict__ vq_b, const int* __restrict__ targets,
    float* __restrict__ vce4) {
    __shared__ short As[2][32 * 32];
    __shared__ short Bs[2][256 * 32];
    __shared__ float part[2][4][32];
    __shared__ float tgtv[32];
    const int tid = threadIdx.x;
    const int w = tid >> 6, l = tid & 63;
    const int bm = blockIdx.x * 32;
    const int g = blockIdx.y;
    const int q = l >> 4, rA = l & 15;
    const int sx = ((l & 3) ^ ((l >> 2) & 3)) * 8;
    const int fx = (q ^ (rA & 3)) * 8;

    const short* gA = A + (size_t)(bm + (l >> 2)) * CH + sx;
    const short* gB = vqT + (size_t)(g * VQS + w * 64 + (l >> 2)) * CH + sx;

    f32x4 acc[2][4] = {};

    for (int k0 = 0; k0 < CH; k0 += 64) {
        if (w == 0) {
#pragma unroll
            for (int rg = 0; rg < 2; rg++) {
                GLD16(gA + (size_t)(rg * 16) * CH + k0,      &As[0][(rg * 16) * 32]);
                GLD16(gA + (size_t)(rg * 16) * CH + k0 + 32, &As[1][(rg * 16) * 32]);
            }
        }
#pragma unroll
        for (int i = 0; i < 4; i++) {
            GLD16(gB + (size_t)(i * 16) * CH + k0,      &Bs[0][(w * 64 + i * 16) * 32]);
            GLD16(gB + (size_t)(i * 16) * CH + k0 + 32, &Bs[1][(w * 64 + i * 16) * 32]);
        }
        __syncthreads();
#pragma unroll
        for (int s = 0; s < 2; s++) {
            bf16x8 a[2], b[4];
#pragma unroll
            for (int m = 0; m < 2; m++)
                a[m] = *(const bf16x8*)(&As[s][(m * 16 + rA) * 32 + fx]);
#pragma unroll
            for (int n = 0; n < 4; n++)
                b[n] = *(const bf16x8*)(&Bs[s][(w * 64 + n * 16 + rA) * 32 + fx]);
#pragma unroll
            for (int m = 0; m < 2; m++)
#pragma unroll
                for (int n = 0; n < 4; n++)
                    acc[m][n] = __builtin_amdgcn_mfma_f32_16x16x32_bf16(b[n], a[m], acc[m][n], 0, 0, 0);
        }
        __syncthreads();
    }

    float pm[2];
#pragma unroll
    for (int m = 0; m < 2; m++) {
        pm[m] = -1e30f;
        int row = m * 16 + rA;
        int t = targets[(size_t)(bm + row) * VQG + g];
#pragma unroll
        for (int n = 0; n < 4; n++) {
            int colb = w * 64 + n * 16 + q * 4;
            float4 bv = *(const float4*)(vq_b + g * VQS + colb);
            float v0 = acc[m][n][0] + bv.x;
            float v1 = acc[m][n][1] + bv.y;
            float v2 = acc[m][n][2] + bv.z;
            float v3 = acc[m][n][3] + bv.w;
            acc[m][n][0] = v0; acc[m][n][1] = v1; acc[m][n][2] = v2; acc[m][n][3] = v3;
            if (colb + 0 == t) tgtv[row] = v0;
            if (colb + 1 == t) tgtv[row] = v1;
            if (colb + 2 == t) tgtv[row] = v2;
            if (colb + 3 == t) tgtv[row] = v3;
            pm[m] = fmaxf(pm[m], fmaxf(fmaxf(v0, v1), fmaxf(v2, v3)));
        }
    }
#pragma unroll
    for (int m = 0; m < 2; m++) {
        pm[m] = fmaxf(pm[m], __shfl_xor(pm[m], 16));
        pm[m] = fmaxf(pm[m], __shfl_xor(pm[m], 32));
    }
    if (q == 0) {
#pragma unroll
        for (int m = 0; m < 2; m++) part[0][w][m * 16 + rA] = pm[m];
    }
    __syncthreads();
    float pmf[2], psum[2];
#pragma unroll
    for (int m = 0; m < 2; m++) {
        int row = m * 16 + rA;
        float mx = fmaxf(fmaxf(part[0][0][row], part[0][1][row]),
                         fmaxf(part[0][2][row], part[0][3][row]));
        pmf[m] = mx;
        float s = 0.f;
#pragma unroll
        for (int n = 0; n < 4; n++)
            s += __expf(acc[m][n][0] - mx) + __expf(acc[m][n][1] - mx)
               + __expf(acc[m][n][2] - mx) + __expf(acc[m][n][3] - mx);
        psum[m] = s;
    }
#pragma unroll
    for (int m = 0; m < 2; m++) {
        psum[m] += __shfl_xor(psum[m], 16);
        psum[m] += __shfl_xor(psum[m], 32);
    }
    if (q == 0) {
#pragma unroll
        for (int m = 0; m < 2; m++) part[1][w][m * 16 + rA] = psum[m];
    }
    __syncthreads();
    if (w == 0 && q == 0) {
#pragma unroll
        for (int m = 0; m < 2; m++) {
            int row = m * 16 + rA;
            float tot = part[1][0][row] + part[1][1][row] + part[1][2][row] + part[1][3][row];
            float lse = pmf[m] + logf(tot);
            vce4[(size_t)(bm + row) * VQG + g] = lse - tgtv[row];
        }
    }
}

// ------- fused QKV-GEMM + window attention; 8 waves, block = (window, head) ------------
__global__ __launch_bounds__(512, 4) void k_attn_fused(
    const unsigned short* __restrict__ hin, const short* __restrict__ Wt,
    const float* __restrict__ bias, short* __restrict__ o, int dil) {
    __shared__ short smem[40960];          // 80 KB union
    short* Asm = smem;                     // phase A: 2 x 256x32 @ 0      (32 KB)
    short* Wsm = smem + 16384;             // phase A: 2 x 96x32  @ 32 KB  (12 KB)
    short* Ql  = smem;                     // phase B: 256x32 @ 0          (16 KB)
    short* Kl  = smem + 8192;              // phase B: 256x32 @ 16 KB
    short* Vt  = smem + 16384;             // phase B: 32x256 @ 32 KB
    short* Pl  = smem + 24576;             // phase B: 8 x 32x64 @ 48 KB   (32 KB)

    const int wid = blockIdx.x, hd = blockIdx.y;
    const int tid = threadIdx.x;
    const int w = tid >> 6, l = tid & 63;
    const int g = l >> 4, c = l & 15;
    const int tbase = (wid / dil) * (PW * dil) + (wid % dil);
    const int sx = ((l & 3) ^ ((l >> 2) & 3)) * 8;
    const int fx = (g ^ (c & 3)) * 8;

    // ---------------- phase A: QKV mini-GEMM ----------------
    f32x4 acc[2][6] = {};
    {
        const int lr = l >> 2;
        const int rw = w * 12 + lr;
        const int seg = rw >> 5, within = rw & 31;
        const short* gW = Wt + (size_t)(seg * 256 + hd * 32 + within) * CH + sx;
        for (int k0 = 0; k0 < CH; k0 += 64) {
#pragma unroll
            for (int h16 = 0; h16 < 2; h16++) {
                int row = w * 32 + h16 * 16 + lr;
                const unsigned short* src = hin + (size_t)(tbase + row * dil) * CH + k0 + sx;
                GLD16(src,      Asm + (w * 32 + h16 * 16) * 32);
                GLD16(src + 32, Asm + 8192 + (w * 32 + h16 * 16) * 32);
            }
            if (l < 48) {
                GLD16(gW + k0,      Wsm + (w * 12) * 32);
                GLD16(gW + k0 + 32, Wsm + 3072 + (w * 12) * 32);
            }
            __syncthreads();
#pragma unroll
            for (int s = 0; s < 2; s++) {
                bf16x8 a[2], b[6];
#pragma unroll
                for (int m = 0; m < 2; m++)
                    a[m] = *(const bf16x8*)(Asm + s * 8192 + (w * 32 + m * 16 + c) * 32 + fx);
#pragma unroll
                for (int n = 0; n < 6; n++)
                    b[n] = *(const bf16x8*)(Wsm + s * 3072 + (n * 16 + c) * 32 + fx);
#pragma unroll
                for (int m = 0; m < 2; m++)
#pragma unroll
                    for (int n = 0; n < 6; n++)
                        acc[m][n] = __builtin_amdgcn_mfma_f32_16x16x32_bf16(b[n], a[m], acc[m][n], 0, 0, 0);
            }
            __syncthreads();
        }
    }
    // ---- scatter Q,K (slot-XOR layout) and V (transposed layout) to LDS ----
#pragma unroll
    for (int m = 0; m < 2; m++) {
        int t = w * 32 + m * 16 + c;
#pragma unroll
        for (int n = 0; n < 6; n++) {
            int seg = n >> 1, n1 = n & 1;
            int colb = n1 * 16 + g * 4;
            float4 bv = *(const float4*)(bias + seg * 256 + hd * 32 + colb);
            float v0 = acc[m][n][0] + bv.x;
            float v1 = acc[m][n][1] + bv.y;
            float v2 = acc[m][n][2] + bv.z;
            float v3 = acc[m][n][3] + bv.w;
            if (seg < 2) {
                short* dst = (seg == 0) ? Ql : Kl;
                int slot = (n1 * 2 + (g >> 1)) ^ (t & 3);
                uint2 pk; pk.x = pack2bf(v0, v1); pk.y = pack2bf(v2, v3);
                *(uint2*)(dst + t * 32 + slot * 8 + (g & 1) * 4) = pk;
            } else {
                int d0 = colb;
                Vt[(d0 + 0) * PW + ((((t >> 3) ^ ((d0 + 0) & 7))) << 3) + (t & 7)] = (short)f2bfu(v0);
                Vt[(d0 + 1) * PW + ((((t >> 3) ^ ((d0 + 1) & 7))) << 3) + (t & 7)] = (short)f2bfu(v1);
                Vt[(d0 + 2) * PW + ((((t >> 3) ^ ((d0 + 2) & 7))) << 3) + (t & 7)] = (short)f2bfu(v2);
                Vt[(d0 + 3) * PW + ((((t >> 3) ^ ((d0 + 3) & 7))) << 3) + (t & 7)] = (short)f2bfu(v3);
            }
        }
    }
    __syncthreads();

    // ---------------- phase B: flash attention ----------------
    bf16x8 qf[2];
#pragma unroll
    for (int qt = 0; qt < 2; qt++) {
        int qrow = w * 32 + qt * 16 + c;
        qf[qt] = *(const bf16x8*)(Ql + qrow * 32 + ((g ^ (qrow & 3)) * 8));
    }

    f32x4 acco[2][2] = {};
    float m_s[2] = {-1e30f, -1e30f};
    float l_s[2] = {0.f, 0.f};
    const float scale = 0.17677669529663687f;

#pragma unroll
    for (int ch = 0; ch < 4; ch++) {
        bf16x8 kf[4];
#pragma unroll
        for (int kvt = 0; kvt < 4; kvt++) {
            int kv = ch * 64 + kvt * 16 + c;
            kf[kvt] = *(const bf16x8*)(Kl + kv * 32 + ((g ^ (kv & 3)) * 8));
        }
        f32x4 accs[4][2] = {};
#pragma unroll
        for (int kvt = 0; kvt < 4; kvt++)
#pragma unroll
            for (int qt = 0; qt < 2; qt++)
                accs[kvt][qt] = __builtin_amdgcn_mfma_f32_16x16x32_bf16(kf[kvt], qf[qt], accs[kvt][qt], 0, 0, 0);

        float fb[2];
#pragma unroll
        for (int qt = 0; qt < 2; qt++) {
            float mx = -1e30f;
#pragma unroll
            for (int kvt = 0; kvt < 4; kvt++) {
                mx = fmaxf(mx, fmaxf(fmaxf(accs[kvt][qt][0], accs[kvt][qt][1]),
                                     fmaxf(accs[kvt][qt][2], accs[kvt][qt][3])));
            }
            mx = fmaxf(mx, __shfl_xor(mx, 16));
            mx = fmaxf(mx, __shfl_xor(mx, 32));
            float mnew = fmaxf(m_s[qt], mx * scale);
            fb[qt] = __expf(m_s[qt] - mnew);
            m_s[qt] = mnew;
        }
#pragma unroll
        for (int mt = 0; mt < 2; mt++) {
            float fo = fb[mt];
#pragma unroll
            for (int r = 0; r < 4; r++) {
                acco[mt][0][r] *= fo;
                acco[mt][1][r] *= fo;
            }
        }
        float rsum[2] = {0.f, 0.f};
#pragma unroll
        for (int kvt = 0; kvt < 4; kvt++) {
            const int cchunk = kvt * 2 + (g >> 1);
            const int koff = (g & 1) << 2;
#pragma unroll
            for (int qt = 0; qt < 2; qt++) {
                float p0 = __expf(accs[kvt][qt][0] * scale - m_s[qt]);
                float p1 = __expf(accs[kvt][qt][1] * scale - m_s[qt]);
                float p2 = __expf(accs[kvt][qt][2] * scale - m_s[qt]);
                float p3 = __expf(accs[kvt][qt][3] * scale - m_s[qt]);
                rsum[qt] += (p0 + p1) + (p2 + p3);
                int qq = qt * 16 + c;
                int phys = cchunk ^ (qq & 7);
                uint2 pk; pk.x = pack2bf(p0, p1); pk.y = pack2bf(p2, p3);
                *(uint2*)(Pl + w * 2048 + qq * 64 + phys * 8 + koff) = pk;
            }
        }
#pragma unroll
        for (int qt = 0; qt < 2; qt++) {
            float s = rsum[qt];
            s += __shfl_xor(s, 16);
            s += __shfl_xor(s, 32);
            l_s[qt] = l_s[qt] * fb[qt] + s;
        }
#pragma unroll
        for (int ks = 0; ks < 2; ks++) {
            bf16x8 pa[2];
#pragma unroll
            for (int mt = 0; mt < 2; mt++) {
                int qq = mt * 16 + c;
                int phys = (ks * 4 + g) ^ (qq & 7);
                pa[mt] = *(const bf16x8*)(Pl + w * 2048 + qq * 64 + phys * 8);
            }
#pragma unroll
            for (int nt = 0; nt < 2; nt++) {
                int d = nt * 16 + c;
                int kvabs = ch * 64 + ks * 32 + g * 8;
                int phys = (kvabs >> 3) ^ (d & 7);
                bf16x8 vb = *(const bf16x8*)(Vt + d * PW + phys * 8);
#pragma unroll
                for (int mt = 0; mt < 2; mt++)
                    acco[mt][nt] = __builtin_amdgcn_mfma_f32_16x16x32_bf16(vb, pa[mt], acco[mt][nt], 0, 0, 0);
            }
        }
    }

#pragma unroll
    for (int mt = 0; mt < 2; mt++) {
        float linv = 1.0f / l_s[mt];
        int qrow = w * 32 + mt * 16 + c;
        size_t trow = (size_t)(tbase + qrow * dil) * CH + hd * DHD;
#pragma unroll
        for (int nt = 0; nt < 2; nt++) {
            ushort4 st = { f2bfu(acco[mt][nt][0] * linv), f2bfu(acco[mt][nt][1] * linv),
                           f2bfu(acco[mt][nt][2] * linv), f2bfu(acco[mt][nt][3] * linv) };
            *(ushort4*)((unsigned short*)o + trow + nt * 16 + g * 4) = st;
        }
    }
}

// ---------------- final reduction ------------------------------------------------------
__global__ void k_reduce(const float* __restrict__ sce, const float* __restrict__ vce4,
                         const int* __restrict__ mask_i, float* __restrict__ out) {
    int tid = threadIdx.x;
    float s1 = 0, s2 = 0, s3 = 0, s4 = 0;
    for (int i = tid; i < NSPLIT; i += 256) { s1 += sce[i]; s2 += (float)mask_i[i]; }
    for (int i = tid; i < NVQ; i += 256) {
        float mv = (float)mask_i[NSPLIT + i];
        float cs = vce4[i * 4 + 0] + vce4[i * 4 + 1] + vce4[i * 4 + 2] + vce4[i * 4 + 3];
        s3 += cs * 0.25f * mv;
        s4 += mv;
    }
    __shared__ float r1[256], r2[256], r3[256], r4[256];
    r1[tid] = s1; r2[tid] = s2; r3[tid] = s3; r4[tid] = s4;
    __syncthreads();
    for (int o = 128; o; o >>= 1) {
        if (tid < o) { r1[tid] += r1[tid + o]; r2[tid] += r2[tid + o];
                       r3[tid] += r3[tid + o]; r4[tid] += r4[tid + o]; }
        __syncthreads();
    }
    if (tid == 0) {
        out[0] = r1[0] / fmaxf(r2[0], 1.0f);
        out[1] = r3[0] / fmaxf(r4[0], 1.0f);
    }
}

// ======================================================================================
extern "C" void kernel_launch(void* const* d_in, const int* in_sizes, int n_in,
                              void* d_out, int out_size, void* d_ws, size_t ws_size,
                              hipStream_t stream) {
    const int*   split      = (const int*)d_in[0];
    const float* zq         = (const float*)d_in[1];
    const int*   targets_vq = (const int*)d_in[2];
    const int*   category   = (const int*)d_in[3];
    const int*   batch_id   = (const int*)d_in[4];
    const void*  mask_raw   = d_in[5];
    const int*   d2b        = (const int*)d_in[6];
    const float* split_emb  = (const float*)d_in[7];
    const float* class_emb  = (const float*)d_in[8];
    const float* vq_proj_w  = (const float*)d_in[9];
    const float* vq_proj_b  = (const float*)d_in[10];
    const float* ln1_s      = (const float*)d_in[11];
    const float* ln1_b      = (const float*)d_in[12];
    const float* qkv_w      = (const float*)d_in[13];
    const float* qkv_b      = (const float*)d_in[14];
    const float* attn_w     = (const float*)d_in[15];
    const float* attn_b     = (const float*)d_in[16];
    const float* ln2_s      = (const float*)d_in[17];
    const float* ln2_b      = (const float*)d_in[18];
    const float* fc1_w      = (const float*)d_in[19];
    const float* fc1_b      = (const float*)d_in[20];
    const float* fc2_w      = (const float*)d_in[21];
    const float* fc2_b      = (const float*)d_in[22];
    const float* lnx_s      = (const float*)d_in[23];
    const float* lnx_b      = (const float*)d_in[24];
    const float* sw         = (const float*)d_in[25];
    const float* sb         = (const float*)d_in[26];
    const float* vq_w       = (const float*)d_in[27];
    const float* vq_b       = (const float*)d_in[28];

    char* ws = (char*)d_ws;
    int* mode   = (int*)ws;
    int* mask_i = (int*)(ws + 256);
    float* sce  = (float*)(ws + 256 + 4 * NTOK);
    float* vce4 = sce + NSPLIT;
    char* p = ws + (1 << 20);
    short* qkvT = (short*)p;  p += (size_t)NL * 768 * CH * 2;
    short* attnT = (short*)p; p += (size_t)NL * CH * CH * 2;
    short* fc1T = (short*)p;  p += (size_t)NL * HIDN * CH * 2;
    short* fc2T = (short*)p;  p += (size_t)NL * CH * HIDN * 2;
    short* vqT = (short*)p;   p += (size_t)HIDN * CH * 2;
    unsigned short* xbv = (unsigned short*)p; p += (size_t)NTOK * CH * 2;
    unsigned short* h_bf = (unsigned short*)p; p += (size_t)NTOK * CH * 2;
    unsigned short* o_bf = (unsigned short*)p; p += (size_t)NTOK * CH * 2;
    short* big = (short*)p;   // fc1-out (bf16)

    k_wt_all<<<833, 256, 0, stream>>>(qkv_w, attn_w, fc1_w, fc2_w, vq_w,
                                      qkvT, attnT, fc1T, fc2T, vqT, mask_raw, mode);
    k_embed_gather<<<NTOK, 256, 0, stream>>>(split, zq, category, batch_id, mask_raw, mode,
                                             mask_i, d2b, split_emb, class_emb,
                                             vq_proj_w, vq_proj_b, ln1_s, ln1_b, xbv, h_bf);

    for (int l = 0; l < NL; l++) {
        int d = (l & 1) ? 2 : 1;
        k_attn_fused<<<dim3(NTOK / PW, NH), 512, 0, stream>>>(
            h_bf, qkvT + (size_t)l * 768 * CH, qkv_b + l * 768, (short*)o_bf, d);
        k_mm_row<1><<<NTOK / 32, 512, 0, stream>>>(
            (const short*)o_bf, attnT + (size_t)l * CH * CH, attn_b + l * CH,
            xbv, ln2_s + l * CH, ln2_b + l * CH, h_bf, nullptr, CH,
            nullptr, nullptr, nullptr, nullptr, nullptr);
        k_mm<1><<<dim3(HIDN / 128, NTOK / 128), 256, 0, stream>>>(
            (const short*)h_bf, fc1T + (size_t)l * HIDN * CH, fc1_b + l * HIDN,
            (unsigned short*)big, HIDN, CH);
        if (l < NL - 1) {
            k_mm_row<1><<<NTOK / 32, 512, 0, stream>>>(
                big, fc2T + (size_t)l * CH * HIDN, fc2_b + l * CH,
                xbv, ln1_s + (l + 1) * CH, ln1_b + (l + 1) * CH, h_bf, nullptr, HIDN,
                nullptr, nullptr, nullptr, nullptr, nullptr);
        } else {
            k_mm_row<2><<<NTOK / 32, 512, 0, stream>>>(
                big, fc2T + (size_t)l * CH * HIDN, fc2_b + l * CH,
                xbv, lnx_s, lnx_b, h_bf, d2b, HIDN,
                split, mask_i, sw, sb, sce);
        }
    }

    k_vq_head<<<dim3(NVQ / 32, VQG), 256, 0, stream>>>(
        (const short*)(h_bf + (size_t)NSPLIT * CH), vqT, vq_b, targets_vq, vce4);
    k_reduce<<<1, 256, 0, stream>>>(sce, vce4, mask_i, (float*)d_out);
}